// Round 1
// baseline (154.036 us; speedup 1.0000x reference)
//
#include <hip/hip_runtime.h>

// ConnectLoss fused kernel v4 for MI355X (gfx950).
//
// v3 post-mortem: main kernel 40.4 us with VALUBusy 48%, HBM 14%, Occupancy
// 17.7% -> latency-bound, not issue-bound. Grid was 1024 blocks = exactly
// 4 blocks/CU (no scheduler slack) and each wave ran a long serial chain of
// 4 channel-pair sections (load -> shuffle -> transcendental loops -> vote).
// v4: one block = ONE row, 4 waves, each wave owns one channel PAIR
// ((0,7),(1,6),(2,5),(3,4)). 4x shorter per-thread chains, 4096 blocks
// (16 blocks/CU available), neighbor loads issued before the sigmoid loops
// so VMEM latency hides under compute. Cross-channel reductions (xmin, vote
// max, edge flag) via one __syncthreads + 20 KB LDS. Math formulas are
// bit-identical to v3 (which verified absmax 0.0).

#define HDIM 512
#define WDIM 512
#define HW (HDIM * WDIM)
#define BATCH 8
#define NBLKX HDIM              // one row per block -> 512 blocks per image
#define NBLK  (NBLKX * BATCH)   // 4096 blocks total

__device__ __forceinline__ float fast_sig(float x) {
    float e = __expf(-fabsf(x));
    float r = __builtin_amdgcn_rcpf(1.0f + e);
    return (x >= 0.0f) ? r : e * r;
}
// sigmoid(x); sp_out = log(1+exp(-|x|)) so softplus(+-x) = max(+-x,0) + sp_out
__device__ __forceinline__ float sig_sp(float x, float& sp_out) {
    float e = __expf(-fabsf(x));
    float d = 1.0f + e;
    sp_out = __logf(d);
    float r = __builtin_amdgcn_rcpf(d);
    return (x >= 0.0f) ? r : e * r;
}

struct Arr10 { float v[10]; };  // cols j0-1 .. j0+8 (halos via wave shuffle)

__device__ __forceinline__ void load8(const float* p, float* o) {
    const float4 a = *(const float4*)p;
    const float4 b = *(const float4*)(p + 4);
    o[0]=a.x; o[1]=a.y; o[2]=a.z; o[3]=a.w;
    o[4]=b.x; o[5]=b.y; o[6]=b.z; o[7]=b.w;
}

__device__ __forceinline__ Arr10 strip10_from(const float* x, int lane) {
    Arr10 r;
    float l = __shfl_up(x[7], 1, 64);
    float h = __shfl_down(x[0], 1, 64);
    r.v[0] = (lane == 0)  ? 0.f : l;    // image-left boundary
    r.v[9] = (lane == 63) ? 0.f : h;    // image-right boundary
#pragma unroll
    for (int k = 0; k < 8; ++k) r.v[k + 1] = x[k];
    return r;
}

__device__ __forceinline__ Arr10 load_strip10(const float* p, int lane, bool valid) {
    float x[8] = {0.f,0.f,0.f,0.f,0.f,0.f,0.f,0.f};
    if (valid) load8(p, x);             // valid is wave-uniform
    return strip10_from(x, lane);
}

__global__ __launch_bounds__(256) void connect_loss_main(
        const float* __restrict__ pred,   // (B, 8, H, W)
        const float* __restrict__ tgt,    // (B, 1, H, W)
        float* __restrict__ partials,     // mode 1: [6][NBLK]
        double* __restrict__ wsd,         // mode 0: 27 doubles
        int mode)
{
    const int b    = blockIdx.y;
    const int i    = blockIdx.x;          // row; whole block works on row i
    const int tid  = threadIdx.x;
    const int lane = tid & 63;
    const int wv   = tid >> 6;            // wave = channel pair (wv, 7-wv)
    const int j0   = lane << 3;
    const int p0   = i * WDIM + j0;
    const bool rm  = (i > 0), rp = (i < HDIM - 1);   // block-uniform now
    const bool l0  = (lane == 0), l63 = (lane == 63);

    const float* tb = tgt  + (size_t)b * HW;
    const float* pb = pred + (size_t)b * 8 * HW;

    __shared__ float xmin_l[4][WDIM];   // per-wave logit min  (8 KB)
    __shared__ float fp_l[4][WDIM];     // per-wave vote max   (8 KB)
    __shared__ float ef_l[WDIM];        // edge flag (wave 3)  (2 KB)
    __shared__ float t_l[WDIM];         // target row i        (2 KB)
    __shared__ float red[4][6];

    // ---------- issue neighbor pred loads EARLY (latency hides under sigmoid
    // loops below). Channel c pairs with channel 7-c at offset Delta_c:
    // c0:(-1,-1) c1:(-1,0) c2:(-1,+1) c3:(0,-1) c4:(0,+1) c5:(+1,-1)
    // c6:(+1,0) c7:(+1,+1). Wave wv votes for (wv, 7-wv). ----------
    float na[8] = {0.f,0.f,0.f,0.f,0.f,0.f,0.f,0.f};  // ch(7-wv) @ row i-1
    float nb[8] = {0.f,0.f,0.f,0.f,0.f,0.f,0.f,0.f};  // ch(wv)   @ row i+1
    if (wv == 0) {
        if (rm) load8(pb + 7 * (size_t)HW + p0 - WDIM, na);
        if (rp) load8(pb + 0 * (size_t)HW + p0 + WDIM, nb);
    } else if (wv == 1) {
        if (rm) load8(pb + 6 * (size_t)HW + p0 - WDIM, na);
        if (rp) load8(pb + 1 * (size_t)HW + p0 + WDIM, nb);
    } else if (wv == 2) {
        if (rm) load8(pb + 5 * (size_t)HW + p0 - WDIM, na);
        if (rp) load8(pb + 2 * (size_t)HW + p0 + WDIM, nb);
    }
    // own channels
    float xa[8], xb[8];
    load8(pb + (size_t)wv * HW + p0, xa);
    load8(pb + (size_t)(7 - wv) * HW + p0, xb);

    // ---------- target strips + per-wave connectivity bits ----------
    Arr10 tm = load_strip10(tb + (rm ? p0 - WDIM : p0), lane, rm);
    Arr10 tc = load_strip10(tb + p0,                    lane, true);
    Arr10 tp = load_strip10(tb + (rp ? p0 + WDIM : p0), lane, rp);

    int maskA = 0, maskB = 0;   // bit k: conn bit for px j0+k, ch wv / 7-wv
    if (wv == 0) {
#pragma unroll
        for (int k = 0; k < 8; ++k) {
            const bool t1 = tc.v[k+1] > 0.5f;
            maskA |= (t1 && tm.v[k]   > 0.5f) ? (1 << k) : 0;  // ch0 (i-1,j-1)
            maskB |= (t1 && tp.v[k+2] > 0.5f) ? (1 << k) : 0;  // ch7 (i+1,j+1)
        }
    } else if (wv == 1) {
#pragma unroll
        for (int k = 0; k < 8; ++k) {
            const bool t1 = tc.v[k+1] > 0.5f;
            maskA |= (t1 && tm.v[k+1] > 0.5f) ? (1 << k) : 0;  // ch1 (i-1,j)
            maskB |= (t1 && tp.v[k+1] > 0.5f) ? (1 << k) : 0;  // ch6 (i+1,j)
        }
    } else if (wv == 2) {
#pragma unroll
        for (int k = 0; k < 8; ++k) {
            const bool t1 = tc.v[k+1] > 0.5f;
            maskA |= (t1 && tm.v[k+2] > 0.5f) ? (1 << k) : 0;  // ch2 (i-1,j+1)
            maskB |= (t1 && tp.v[k]   > 0.5f) ? (1 << k) : 0;  // ch5 (i+1,j-1)
        }
    } else {
        float efv[8], tv[8];
#pragma unroll
        for (int k = 0; k < 8; ++k) {
            const float t_ = tc.v[k+1];
            const bool t1 = t_ > 0.5f;
            maskA |= (t1 && tc.v[k]   > 0.5f) ? (1 << k) : 0;  // ch3 (i,j-1)
            maskB |= (t1 && tc.v[k+2] > 0.5f) ? (1 << k) : 0;  // ch4 (i,j+1)
            const float s8 = tm.v[k] + tm.v[k+1] + tm.v[k+2]
                           + tc.v[k] + tc.v[k+2]
                           + tp.v[k] + tp.v[k+1] + tp.v[k+2];
            const float sc = t_ * s8;
            efv[k] = (sc < 8.0f && sc > 0.0f) ? 1.f : 0.f;
            tv[k] = t_;
        }
        *(float4*)&ef_l[j0]     = make_float4(efv[0],efv[1],efv[2],efv[3]);
        *(float4*)&ef_l[j0 + 4] = make_float4(efv[4],efv[5],efv[6],efv[7]);
        *(float4*)&t_l[j0]      = make_float4(tv[0],tv[1],tv[2],tv[3]);
        *(float4*)&t_l[j0 + 4]  = make_float4(tv[4],tv[5],tv[6],tv[7]);
    }

    // ---------- own-channel math: sigmoid + BCE + logit min ----------
    // (covers the in-flight na/nb load latency)
    float sa[8], sb[8], lmin[8], lfp[8];
    float bce = 0.f;
#pragma unroll
    for (int k = 0; k < 8; ++k) {
        float sp;
        sa[k] = sig_sp(xa[k], sp);
        const float sel = ((maskA >> k) & 1) ? -xa[k] : xa[k];
        bce += fminf(fmaxf(sel, 0.f) + sp, 100.f);   // == v3's sp_pos/sp_neg select
        lmin[k] = xa[k];
    }
#pragma unroll
    for (int k = 0; k < 8; ++k) {
        float sp;
        sb[k] = sig_sp(xb[k], sp);
        const float sel = ((maskB >> k) & 1) ? -xb[k] : xb[k];
        bce += fminf(fmaxf(sel, 0.f) + sp, 100.f);
        lmin[k] = fminf(lmin[k], xb[k]);
        lfp[k] = 0.f;
    }

    // ---------- votes: fp = max(s_own * sigmoid(neighbor)) ----------
    auto vote = [&](const float* s, const Arr10& n, int off, bool rv) {
#pragma unroll
        for (int k = 0; k < 8; ++k) {
            bool ok = rv;
            if (off == 0 && k == 0) ok = ok && !l0;
            if (off == 2 && k == 7) ok = ok && !l63;
            const float q = ok ? fast_sig(n.v[k + off]) : 0.f;
            lfp[k] = fmaxf(lfp[k], s[k] * q);
        }
    };

    if (wv == 0) {          // d0 uses ch7@(i-1,j-1); d7 uses ch0@(i+1,j+1)
        Arr10 nA = strip10_from(na, lane);
        Arr10 nB = strip10_from(nb, lane);
        vote(sa, nA, 0, rm);
        vote(sb, nB, 2, rp);
    } else if (wv == 1) {   // d1 uses ch6@(i-1,j); d6 uses ch1@(i+1,j)
        Arr10 nA = strip10_from(na, lane);
        Arr10 nB = strip10_from(nb, lane);
        vote(sa, nA, 1, rm);
        vote(sb, nB, 1, rp);
    } else if (wv == 2) {   // d2 uses ch5@(i-1,j+1); d5 uses ch2@(i+1,j-1)
        Arr10 nA = strip10_from(na, lane);
        Arr10 nB = strip10_from(nb, lane);
        vote(sa, nA, 2, rm);
        vote(sb, nB, 0, rp);
    } else {                // d3 uses ch4@(i,j-1); d4 uses ch3@(i,j+1)
        Arr10 nA = strip10_from(xb, lane);
        Arr10 nB = strip10_from(xa, lane);
        vote(sa, nA, 0, true);
        vote(sb, nB, 2, true);
    }

    // ---------- cross-wave combine via LDS ----------
    *(float4*)&xmin_l[wv][j0]     = make_float4(lmin[0],lmin[1],lmin[2],lmin[3]);
    *(float4*)&xmin_l[wv][j0 + 4] = make_float4(lmin[4],lmin[5],lmin[6],lmin[7]);
    *(float4*)&fp_l[wv][j0]       = make_float4(lfp[0],lfp[1],lfp[2],lfp[3]);
    *(float4*)&fp_l[wv][j0 + 4]   = make_float4(lfp[4],lfp[5],lfp[6],lfp[7]);
    __syncthreads();

    // ---------- epilogue: edge loss + dice partials (128 px per wave,
    // lane-consecutive px -> conflict-free LDS reads) ----------
    float e_num = 0.f, e_den = 0.f, inter = 0.f, fpsum = 0.f, tsum = 0.f;
#pragma unroll
    for (int u = 0; u < 2; ++u) {
        const int px = (wv << 7) + (u << 6) + lane;
        const float m   = fminf(fminf(xmin_l[0][px], xmin_l[1][px]),
                                fminf(xmin_l[2][px], xmin_l[3][px]));
        const float fpv = fmaxf(fmaxf(fp_l[0][px], fp_l[1][px]),
                                fmaxf(fp_l[2][px], fp_l[3][px]));
        const float ef = ef_l[px];
        const float t_ = t_l[px];
        float sp;
        const float pmin = sig_sp(m, sp);                // sigmoid monotone
        e_num += ef * fminf(fmaxf(m, 0.f) + sp, 100.f);  // softplus(xmin)
        e_den += ef * pmin;
        inter += fpv * t_;
        fpsum += fpv;
        tsum  += t_;
    }

    // ---------- block reduction of 6 partials ----------
    float vals[6] = {bce, e_num, e_den, inter, fpsum, tsum};
#pragma unroll
    for (int k = 0; k < 6; ++k) {
        float v = vals[k];
#pragma unroll
        for (int o = 32; o > 0; o >>= 1) v += __shfl_down(v, o, 64);
        if (lane == 0) red[wv][k] = v;
    }
    __syncthreads();
    if (tid < 6) {
        const int k = tid;
        const float sum = red[0][k] + red[1][k] + red[2][k] + red[3][k];
        if (mode == 1) {
            partials[k * NBLK + b * NBLKX + blockIdx.x] = sum;
        } else {
            double* dst;
            switch (k) {
                case 0:  dst = wsd + 0;       break;
                case 1:  dst = wsd + 1;       break;
                case 2:  dst = wsd + 2;       break;
                case 3:  dst = wsd + 3 + b;   break;
                case 4:  dst = wsd + 11 + b;  break;
                default: dst = wsd + 19 + b;  break;
            }
            atomicAdd(dst, (double)sum);
        }
    }
}

__global__ __launch_bounds__(256) void connect_loss_final(
        const float* __restrict__ partials,
        const double* __restrict__ wsd,
        float* __restrict__ out, int mode)
{
    __shared__ double red4[4];
    __shared__ double gsum[3];
    __shared__ double bsum[3][BATCH];
    const int t = threadIdx.x;

    if (mode == 1) {
        const int lane = t & 63, wid = t >> 6;
        {   // per-batch categories (k=3,4,5): 8 groups of 32 lanes
            const int g = t >> 5, e = t & 31;
#pragma unroll
            for (int k = 3; k < 6; ++k) {
                double v = 0.0;
                for (int m = e; m < NBLKX; m += 32)
                    v += (double)partials[k * NBLK + g * NBLKX + m];
                for (int o = 16; o > 0; o >>= 1) v += __shfl_down(v, o, 32);
                if (e == 0) bsum[k - 3][g] = v;
            }
        }
        for (int k = 0; k < 3; ++k) {   // global categories
            double v = 0.0;
            for (int idx = t; idx < NBLK; idx += 256)
                v += (double)partials[k * NBLK + idx];
            for (int o = 32; o > 0; o >>= 1) v += __shfl_down(v, o, 64);
            if (lane == 0) red4[wid] = v;
            __syncthreads();
            if (t == 0) gsum[k] = red4[0] + red4[1] + red4[2] + red4[3];
            __syncthreads();
        }
        if (t == 0) {
            const double conn_loss = gsum[0] / (double)((size_t)BATCH * 8 * HW);
            const double edge_loss = gsum[1] / gsum[2];
            double seg = 0.0;
            for (int bb = 0; bb < BATCH; ++bb) {
                const double dice = (2.0 * bsum[0][bb] + 1.0)
                                  / (bsum[1][bb] + bsum[2][bb] + 1.0);
                seg += 1.0 - dice;
            }
            out[0] = (float)(conn_loss + edge_loss + seg / (double)BATCH);
        }
    } else if (t == 0) {
        const double conn_loss = wsd[0] / (double)((size_t)BATCH * 8 * HW);
        const double edge_loss = wsd[1] / wsd[2];
        double seg = 0.0;
        for (int bb = 0; bb < BATCH; ++bb) {
            const double dice = (2.0 * wsd[3 + bb] + 1.0)
                              / (wsd[11 + bb] + wsd[19 + bb] + 1.0);
            seg += 1.0 - dice;
        }
        out[0] = (float)(conn_loss + edge_loss + seg / (double)BATCH);
    }
}

extern "C" void kernel_launch(void* const* d_in, const int* in_sizes, int n_in,
                              void* d_out, int out_size, void* d_ws, size_t ws_size,
                              hipStream_t stream)
{
    const float* pred = (const float*)d_in[0];   // (8, 8, 512, 512)
    const float* tgt  = (const float*)d_in[1];   // (8, 1, 512, 512)
    // d_in[2]/d_in[3] (hori/verti) are exact one-pixel shift permutation
    // matrices -> implemented as index shifts (verified earlier, absmax 0).

    const dim3 grid(NBLKX, BATCH);
    const size_t needA = (size_t)6 * NBLK * sizeof(float);

    if (ws_size >= needA) {
        float* partials = (float*)d_ws;
        connect_loss_main<<<grid, 256, 0, stream>>>(pred, tgt, partials, nullptr, 1);
        connect_loss_final<<<1, 256, 0, stream>>>(partials, nullptr, (float*)d_out, 1);
    } else {
        double* wsd = (double*)d_ws;
        hipMemsetAsync(d_ws, 0, 27 * sizeof(double), stream);
        connect_loss_main<<<grid, 256, 0, stream>>>(pred, tgt, nullptr, wsd, 0);
        connect_loss_final<<<1, 1, 0, stream>>>(nullptr, wsd, (float*)d_out, 0);
    }
}

// Round 3
// 128.090 us; speedup vs baseline: 1.2026x; 1.2026x over previous
//
#include <hip/hip_runtime.h>

// ConnectLoss fused kernel v5 for MI355X (gfx950).  (Round-2 resubmit: the
// Round-1 bench died on container acquisition, not on the kernel.)
//
// v4 post-mortem: splitting rows across waves + [6][4096] partials regressed
// total 133->154 us (scattered partials / 4x final work); reverted.
// v5 = v3 (verified 133.4 us, absmax 0.0) with ONE change: software-pipelined
// section loads. v3's main was latency-bound (VALUBusy 48%, HBM 14%): each
// wave exposed 4 sequential VMEM round trips, one per channel-pair section.
// v5 ping-pongs two register buffer sets (A/B): target rows + sections 0,1
// load at the top; section s+1's loads issue while section s computes, so
// every load's ~500cy latency hides under the previous section's sigmoid
// chain. Accumulation order is bit-identical to v3.

#define HDIM 512
#define WDIM 512
#define HW (HDIM * WDIM)
#define BATCH 8
#define ROWS_PER_BLOCK 4
#define NBLKX (HDIM / ROWS_PER_BLOCK)   // 128 blocks per batch image
#define NBLK  (NBLKX * BATCH)           // 1024 blocks total

__device__ __forceinline__ float fast_sig(float x) {
    float e = __expf(-fabsf(x));
    float r = __builtin_amdgcn_rcpf(1.0f + e);
    return (x >= 0.0f) ? r : e * r;
}
// sigmoid(x); sp_out = log(1+exp(-|x|)) so softplus(+-x) = max(+-x,0) + sp_out
__device__ __forceinline__ float sig_sp(float x, float& sp_out) {
    float e = __expf(-fabsf(x));
    float d = 1.0f + e;
    sp_out = __logf(d);
    float r = __builtin_amdgcn_rcpf(d);
    return (x >= 0.0f) ? r : e * r;
}

struct Arr10 { float v[10]; };  // cols j0-1 .. j0+8 (halos via wave shuffle)

__device__ __forceinline__ void load8(const float* p, float* o) {
    const float4 a = *(const float4*)p;
    const float4 b = *(const float4*)(p + 4);
    o[0]=a.x; o[1]=a.y; o[2]=a.z; o[3]=a.w;
    o[4]=b.x; o[5]=b.y; o[6]=b.z; o[7]=b.w;
}

__device__ __forceinline__ void zero8(float* o) {
#pragma unroll
    for (int k = 0; k < 8; ++k) o[k] = 0.f;
}

__device__ __forceinline__ Arr10 strip10_from(const float* x, int lane) {
    Arr10 r;
    float l = __shfl_up(x[7], 1, 64);
    float h = __shfl_down(x[0], 1, 64);
    r.v[0] = (lane == 0)  ? 0.f : l;    // image-left boundary
    r.v[9] = (lane == 63) ? 0.f : h;    // image-right boundary
#pragma unroll
    for (int k = 0; k < 8; ++k) r.v[k + 1] = x[k];
    return r;
}

__global__ __launch_bounds__(256) void connect_loss_main(
        const float* __restrict__ pred,   // (B, 8, H, W)
        const float* __restrict__ tgt,    // (B, 1, H, W)
        float* __restrict__ partials,     // mode 1: [6][NBLK]
        double* __restrict__ wsd,         // mode 0: 27 doubles
        int mode)
{
    const int b    = blockIdx.y;
    const int tid  = threadIdx.x;
    const int lane = tid & 63;
    const int wv   = tid >> 6;
    const int i    = blockIdx.x * ROWS_PER_BLOCK + wv;  // wave == one row
    const int j0   = lane << 3;
    const int p0   = i * WDIM + j0;
    const bool rm  = (i > 0), rp = (i < HDIM - 1);
    const bool l0  = (lane == 0), l63 = (lane == 63);

    const float* tb = tgt  + (size_t)b * HW;
    const float* pb = pred + (size_t)b * 8 * HW;

    // ---------- issue ALL early loads first: target rows + sections 0,1 ----
    // Section s pairs channels (s, 7-s). Ra = ch(7-s) @ row i-1 (for vote of
    // d_s); Rb = ch(s) @ row i+1 (for vote of d_{7-s}).
    float t0[8], t1[8], t2[8];
    zero8(t0); zero8(t2);
    if (rm) load8(tb + p0 - WDIM, t0);
    load8(tb + p0, t1);
    if (rp) load8(tb + p0 + WDIM, t2);

    float Axa[8], Axb[8], Ara[8], Arb[8];
    float Bxa[8], Bxb[8], Bra[8], Brb[8];

    auto pload = [&](int cA, int cB, float* Xa, float* Xb, float* Ra, float* Rb) {
        load8(pb + (size_t)cA * HW + p0, Xa);
        load8(pb + (size_t)cB * HW + p0, Xb);
        if (rm) load8(pb + (size_t)cB * HW + p0 - WDIM, Ra); else zero8(Ra);
        if (rp) load8(pb + (size_t)cA * HW + p0 + WDIM, Rb); else zero8(Rb);
    };
    pload(0, 7, Axa, Axb, Ara, Arb);        // section 0
    pload(1, 6, Bxa, Bxb, Bra, Brb);        // section 1 (prefetch)

    // ---------- target strips + conn/edge bits (covers pred load latency) --
    Arr10 tm = strip10_from(t0, lane);
    Arr10 tc = strip10_from(t1, lane);
    Arr10 tp = strip10_from(t2, lane);

    int mb[8];
#pragma unroll
    for (int k = 0; k < 8; ++k) {
        const float t_ = tc.v[k + 1];
        const float s8 = tm.v[k] + tm.v[k+1] + tm.v[k+2]
                       + tc.v[k] + tc.v[k+2]
                       + tp.v[k] + tp.v[k+1] + tp.v[k+2];
        const float sc = t_ * s8;
        int bits = (sc < 8.0f && sc > 0.0f) ? 256 : 0;
        if (t_ > 0.5f) {
            bits |= (tm.v[k]   > 0.5f ?   1 : 0);
            bits |= (tm.v[k+1] > 0.5f ?   2 : 0);
            bits |= (tm.v[k+2] > 0.5f ?   4 : 0);
            bits |= (tc.v[k]   > 0.5f ?   8 : 0);
            bits |= (tc.v[k+2] > 0.5f ?  16 : 0);
            bits |= (tp.v[k]   > 0.5f ?  32 : 0);
            bits |= (tp.v[k+1] > 0.5f ?  64 : 0);
            bits |= (tp.v[k+2] > 0.5f ? 128 : 0);
        }
        mb[k] = bits;
    }

    float fp[8], xmin[8], bce = 0.f;
#pragma unroll
    for (int k = 0; k < 8; ++k) { fp[k] = 0.f; xmin[k] = 1e30f; }

    // own-channel math: sigmoid + BCE (logit-space softplus) + xmin
    auto own_ch = [&](int c, const float* x, float* s) {
#pragma unroll
        for (int k = 0; k < 8; ++k) {
            float sp;
            const float sv = sig_sp(x[k], sp);
            s[k] = sv;
            xmin[k] = fminf(xmin[k], x[k]);
            const float sp_pos = fmaxf( x[k], 0.f) + sp;  // softplus(x)
            const float sp_neg = fmaxf(-x[k], 0.f) + sp;  // softplus(-x)
            bce += ((mb[k] >> c) & 1) ? fminf(sp_neg, 100.f)
                                      : fminf(sp_pos, 100.f);
        }
    };
    // vote: fp[k] = max(fp[k], s[k] * sigmoid(neigh)); off 0/1/2 = col -1/0/+1
    auto vote = [&](const float* s, const Arr10& n, int off, bool rv) {
#pragma unroll
        for (int k = 0; k < 8; ++k) {
            bool ok = rv;
            if (off == 0 && k == 0) ok = ok && !l0;
            if (off == 2 && k == 7) ok = ok && !l63;
            const float q = ok ? fast_sig(n.v[k + off]) : 0.f;
            fp[k] = fmaxf(fp[k], s[k] * q);
        }
    };
    // one channel-pair section: strips, own math, votes (identical order/math
    // to v3's per-pair blocks)
    auto section = [&](int cA, int cB, const float* Xa, const float* Xb,
                       const float* Ra, const float* Rb,
                       int offA, int offB, bool gA, bool gB) {
        Arr10 nA = strip10_from(Ra, lane);
        Arr10 nB = strip10_from(Rb, lane);
        float s_a[8], s_b[8];
        own_ch(cA, Xa, s_a);
        own_ch(cB, Xb, s_b);
        vote(s_a, nA, offA, gA);
        vote(s_b, nB, offB, gB);
    };

    // ---------- pipelined sections: compute s while s+1 loads are in flight
    section(0, 7, Axa, Axb, Ara, Arb, 0, 2, rm, rp);
    pload(2, 5, Axa, Axb, Ara, Arb);        // section 2 (prefetch into A)
    section(1, 6, Bxa, Bxb, Bra, Brb, 1, 1, rm, rp);
    load8(pb + 3 * (size_t)HW + p0, Bxa);   // section 3: in-row pair (3,4)
    load8(pb + 4 * (size_t)HW + p0, Bxb);
    section(2, 5, Axa, Axb, Ara, Arb, 2, 0, rm, rp);
    section(3, 4, Bxa, Bxb, Bxb, Bxa, 0, 2, true, true);

    // ---------- epilogue: edge loss + dice partials ----------
    float e_num = 0.f, e_den = 0.f, inter = 0.f, fpsum = 0.f, tsum = 0.f;
#pragma unroll
    for (int k = 0; k < 8; ++k) {
        const float ef = (mb[k] & 256) ? 1.f : 0.f;
        const float m  = xmin[k];
        const float t_ = tc.v[k + 1];
        float sp;
        const float pmin = sig_sp(m, sp);           // sigmoid monotone
        e_num += ef * fminf(fmaxf(m, 0.f) + sp, 100.f);  // softplus(xmin)
        e_den += ef * pmin;
        inter += fp[k] * t_;
        fpsum += fp[k];
        tsum  += t_;
    }

    // ---------- block reduction of 6 partials ----------
    float vals[6] = {bce, e_num, e_den, inter, fpsum, tsum};
    __shared__ float red[4][6];
#pragma unroll
    for (int k = 0; k < 6; ++k) {
        float v = vals[k];
#pragma unroll
        for (int o = 32; o > 0; o >>= 1) v += __shfl_down(v, o, 64);
        if (lane == 0) red[wv][k] = v;
    }
    __syncthreads();
    if (tid < 6) {
        const int k = tid;
        const float sum = red[0][k] + red[1][k] + red[2][k] + red[3][k];
        if (mode == 1) {
            partials[k * NBLK + b * NBLKX + blockIdx.x] = sum;
        } else {
            double* dst;
            switch (k) {
                case 0:  dst = wsd + 0;       break;
                case 1:  dst = wsd + 1;       break;
                case 2:  dst = wsd + 2;       break;
                case 3:  dst = wsd + 3 + b;   break;
                case 4:  dst = wsd + 11 + b;  break;
                default: dst = wsd + 19 + b;  break;
            }
            atomicAdd(dst, (double)sum);
        }
    }
}

__global__ __launch_bounds__(256) void connect_loss_final(
        const float* __restrict__ partials,
        const double* __restrict__ wsd,
        float* __restrict__ out, int mode)
{
    __shared__ double red4[4];
    __shared__ double gsum[3];
    __shared__ double bsum[3][BATCH];
    const int t = threadIdx.x;

    if (mode == 1) {
        const int lane = t & 63, wid = t >> 6;
        {   // per-batch categories (k=3,4,5): 8 groups of 32 lanes
            const int g = t >> 5, e = t & 31;
#pragma unroll
            for (int k = 3; k < 6; ++k) {
                double v = 0.0;
                for (int m = e; m < NBLKX; m += 32)
                    v += (double)partials[k * NBLK + g * NBLKX + m];
                for (int o = 16; o > 0; o >>= 1) v += __shfl_down(v, o, 32);
                if (e == 0) bsum[k - 3][g] = v;
            }
        }
        for (int k = 0; k < 3; ++k) {   // global categories
            double v = 0.0;
            for (int idx = t; idx < NBLK; idx += 256)
                v += (double)partials[k * NBLK + idx];
            for (int o = 32; o > 0; o >>= 1) v += __shfl_down(v, o, 64);
            if (lane == 0) red4[wid] = v;
            __syncthreads();
            if (t == 0) gsum[k] = red4[0] + red4[1] + red4[2] + red4[3];
            __syncthreads();
        }
        if (t == 0) {
            const double conn_loss = gsum[0] / (double)((size_t)BATCH * 8 * HW);
            const double edge_loss = gsum[1] / gsum[2];
            double seg = 0.0;
            for (int bb = 0; bb < BATCH; ++bb) {
                const double dice = (2.0 * bsum[0][bb] + 1.0)
                                  / (bsum[1][bb] + bsum[2][bb] + 1.0);
                seg += 1.0 - dice;
            }
            out[0] = (float)(conn_loss + edge_loss + seg / (double)BATCH);
        }
    } else if (t == 0) {
        const double conn_loss = wsd[0] / (double)((size_t)BATCH * 8 * HW);
        const double edge_loss = wsd[1] / wsd[2];
        double seg = 0.0;
        for (int bb = 0; bb < BATCH; ++bb) {
            const double dice = (2.0 * wsd[3 + bb] + 1.0)
                              / (wsd[11 + bb] + wsd[19 + bb] + 1.0);
            seg += 1.0 - dice;
        }
        out[0] = (float)(conn_loss + edge_loss + seg / (double)BATCH);
    }
}

extern "C" void kernel_launch(void* const* d_in, const int* in_sizes, int n_in,
                              void* d_out, int out_size, void* d_ws, size_t ws_size,
                              hipStream_t stream)
{
    const float* pred = (const float*)d_in[0];   // (8, 8, 512, 512)
    const float* tgt  = (const float*)d_in[1];   // (8, 1, 512, 512)
    // d_in[2]/d_in[3] (hori/verti) are exact one-pixel shift permutation
    // matrices -> implemented as index shifts (verified earlier, absmax 0).

    const dim3 grid(NBLKX, BATCH);
    const size_t needA = (size_t)6 * NBLK * sizeof(float);

    if (ws_size >= needA) {
        float* partials = (float*)d_ws;
        connect_loss_main<<<grid, 256, 0, stream>>>(pred, tgt, partials, nullptr, 1);
        connect_loss_final<<<1, 256, 0, stream>>>(partials, nullptr, (float*)d_out, 1);
    } else {
        double* wsd = (double*)d_ws;
        hipMemsetAsync(d_ws, 0, 27 * sizeof(double), stream);
        connect_loss_main<<<grid, 256, 0, stream>>>(pred, tgt, nullptr, wsd, 0);
        connect_loss_final<<<1, 1, 0, stream>>>(nullptr, wsd, (float*)d_out, 0);
    }
}